// Round 4
// baseline (302.545 us; speedup 1.0000x reference)
//
#include <hip/hip_runtime.h>
#include <hip/hip_bf16.h>
#include <stdint.h>

// ---------------------------------------------------------------------------
// TensorNet: fused encoder MLP (128->256->256->256, relu) over 32x4096 tokens,
// per-batch mean -> p = relu(m^2) -> decoder MLP (256->512->512->10).
//
// R19: MTILE 64 -> 48 (LDS 32KB -> 24KB -> 6 blocks/CU, +20% resident waves)
// + __launch_bounds__(256,6) to pin VGPR <= 85 + s_setprio(1) around MFMA
// bursts (independent staggered blocks = the regime where it helps).
// Rationale: counters show NOTHING saturated (true matrix-pipe busy ~10%,
// VALUBusy==MfmaUtil because the derived counter counts MFMA as VALU);
// kernel is concurrency-bound; R17's +1 block/CU -> -17% was the only
// lever that paid. Last tile per batch has 16 valid tokens (zero-padded,
// sum-masked). Weight L2 traffic 671->880MB, far under L2 BW.
//
// Explored & rejected (evidence in session log):
//  - R18 wave->token remap (L1-shared a-frags): 4x per-wave a-loads,
//    VGPR 144, occupancy 11.5% -> encoder 185us. REVERTED.
//  - MTILE=128 acc[4][8]: 2 blocks/CU, encoder 74-83us (R16).
//  - __launch_bounds__(256,4) with 64-acc: forced VGPR 64 -> spills (R5).
//  - direct-global layer-1 B-frags + shfl reduce: 4x x-reads (R5/R6).
//  - manual a-frag ping-pong: compiler already schedules (R13).
//  - cooperative single-kernel: graph-capture fails (R11).
//  - decoder fused into encoder tail: encoder 67->140us (R14/R15).
// R17 wins kept: XOR-swizzled LDS, bias-init acc, 128-block decoder,
// out pre-init'd to c3 by pack.
// ---------------------------------------------------------------------------

#define NIN   128
#define NHID  256
#define NDEC  512
#define NOUTC 10
#define BATCH 32
#define NTOK  4096
#define MTILE 48
#define TPB   86                          // ceil(4096/48) tiles per batch
#define NBLK  (BATCH * TPB)               // 2752 encoder tiles

#define SWZ(t) (((t) & 7) << 4)          // XOR swizzle, bits 4-6

typedef short bf16x8 __attribute__((ext_vector_type(8)));
typedef float floatx4 __attribute__((ext_vector_type(4)));

__device__ __forceinline__ uint16_t f2b(float f) {
  union { uint32_t u; float f; } v; v.f = f;
  uint32_t r = v.u + 0x7FFFu + ((v.u >> 16) & 1u);   // RNE
  return (uint16_t)(r >> 16);
}
__device__ __forceinline__ uint32_t pkbf(float lo, float hi) {
  __hip_bfloat162 h = __float22bfloat162_rn(float2{lo, hi});  // v_cvt_pk_bf16_f32
  union { __hip_bfloat162 h; uint32_t u; } c; c.h = h;
  return c.u;
}

// ---------------------------------------------------------------------------
// Pack W1/W2/W3 (fp32 [K][256] row-major) into bf16 MFMA-A-fragment order.
// Also zero-inits msum and pre-loads out with c3 (decoder atomics accumulate
// on top; pack -> encoder -> decoder are stream-ordered).
// ---------------------------------------------------------------------------
__global__ __launch_bounds__(256) void pack_weights(
    const float* __restrict__ W1, const float* __restrict__ W2,
    const float* __restrict__ W3, const float* __restrict__ c3,
    uint16_t* __restrict__ pW, float* __restrict__ msum,
    float* __restrict__ out) {
  int p = blockIdx.x * blockDim.x + threadIdx.x;
  if (p < BATCH * NHID) msum[p] = 0.f;
  if (p < BATCH * NOUTC) out[p] = c3[p % NOUTC];
  const float* W; int K; int base;
  if (p < 32768)      { W = W1; K = NIN;  base = 0; }
  else if (p < 98304) { W = W2; K = NHID; base = 32768; p -= 32768; }
  else                { W = W3; K = NHID; base = 98304; p -= 98304; }
  int j    = p & 7;
  int ln   = (p >> 3) & 63;
  int rest = p >> 9;
  int KC = K >> 5;
  int kc = rest % KC;
  int mt = rest / KC;
  int m = mt * 16 + (ln & 15);
  int k = kc * 32 + ((ln >> 4) << 3) + j;
  pW[base + (((mt * KC + kc) * 64 + ln) << 3) + j] = f2b(W[k * NHID + m]);
}

// ---------------------------------------------------------------------------
// Fused encoder. Block = 256 thr (4 waves), 48 tokens. Wave w owns hidden
// rows [64w,64w+64). LDS = 24576 B -> 6 blocks/CU; (256,6) pins VGPR<=85
// (acc is 48 VGPR now, fits). Last tile/batch: 16 valid tokens, zero-padded;
// padded columns flow independently and are masked out of the token-sum.
// ---------------------------------------------------------------------------
__global__ __launch_bounds__(256, 6) void encoder(
    const float* __restrict__ x,        // [BATCH*NTOK][NIN] fp32
    const uint16_t* __restrict__ pW,
    const float* __restrict__ b1,
    const float* __restrict__ b2,
    const float* __restrict__ b3,
    float* __restrict__ msum) {         // [BATCH][NHID] fp32 accum
  __shared__ __align__(16) uint8_t Hs[MTILE * 512];   // 24576 B

  const int tid  = threadIdx.x;
  const int wave = tid >> 6;
  const int lane = tid & 63;
  const int l15  = lane & 15;
  const int q    = lane >> 4;
  const int batch = blockIdx.x / TPB;
  const int tile  = blockIdx.x - batch * TPB;
  const int valid = (tile == TPB - 1) ? (NTOK - (TPB - 1) * MTILE) : MTILE; // 16 or 48

  const uint16_t* pW1 = pW;             // KC=4
  const uint16_t* pW2 = pW + 32768;     // KC=8
  const uint16_t* pW3 = pW + 98304;     // KC=8

  // ---- stage x tile: 48 tokens x 128 ch fp32 -> bf16, row stride 256B ----
  {
    const float4* xv = (const float4*)(x + (size_t)(batch * NTOK + tile * MTILE) * NIN);
#pragma unroll
    for (int i = 0; i < 3; ++i) {
      const int u = tid + i * 256;            // 8-float unit, 0..767
      const int row = u >> 4;                 // token 0..47
      const int cb  = (u & 15) << 4;          // byte col 0..240
      uint4 w = make_uint4(0u, 0u, 0u, 0u);
      if (row < valid) {
        float4 va = xv[2 * u];
        float4 vb = xv[2 * u + 1];
        w = make_uint4(pkbf(va.x, va.y), pkbf(va.z, va.w),
                       pkbf(vb.x, vb.y), pkbf(vb.z, vb.w));
      }
      *(uint4*)&Hs[row * 256 + (cb ^ SWZ(row))] = w;
    }
  }
  __syncthreads();

  floatx4 acc[4][3];   // [jt][tt]

  // ---- layer 1: K = 128, A = W1^T, B = x; acc init = bias ----
#pragma unroll
  for (int jt = 0; jt < 4; ++jt) {
    const float4 bb = *(const float4*)&b1[wave * 64 + jt * 16 + q * 4];
#pragma unroll
    for (int tt = 0; tt < 3; ++tt)
      acc[jt][tt] = (floatx4){bb.x, bb.y, bb.z, bb.w};
  }
#pragma unroll
  for (int kc = 0; kc < 4; ++kc) {
    bf16x8 a[4], b[3];
#pragma unroll
    for (int jt = 0; jt < 4; ++jt)
      a[jt] = *(const bf16x8*)(pW1 + ((((wave * 4 + jt) * 4 + kc) * 64 + lane) << 3));
#pragma unroll
    for (int tt = 0; tt < 3; ++tt) {
      const int t = tt * 16 + l15;
      b[tt] = *(const bf16x8*)&Hs[t * 256 + ((kc * 64 + q * 16) ^ SWZ(t))];
    }
    __builtin_amdgcn_s_setprio(1);
#pragma unroll
    for (int jt = 0; jt < 4; ++jt)
#pragma unroll
      for (int tt = 0; tt < 3; ++tt)
        acc[jt][tt] = __builtin_amdgcn_mfma_f32_16x16x32_bf16(
            a[jt], b[tt], acc[jt][tt], 0, 0, 0);
    __builtin_amdgcn_s_setprio(0);
  }
  __syncthreads();   // x reads done before h1 overwrites

#pragma unroll
  for (int jt = 0; jt < 4; ++jt) {
    const int cb = (wave * 64 + jt * 16 + q * 4) * 2;
#pragma unroll
    for (int tt = 0; tt < 3; ++tt) {
      const int t = tt * 16 + l15;
      float v0 = fmaxf(acc[jt][tt][0], 0.f);
      float v1 = fmaxf(acc[jt][tt][1], 0.f);
      float v2 = fmaxf(acc[jt][tt][2], 0.f);
      float v3 = fmaxf(acc[jt][tt][3], 0.f);
      *(uint2*)&Hs[t * 512 + (cb ^ SWZ(t))] = make_uint2(pkbf(v0, v1), pkbf(v2, v3));
    }
  }
  __syncthreads();

  // ---- layer 2: K = 256, A = W2^T, B = h1 ----
#pragma unroll
  for (int jt = 0; jt < 4; ++jt) {
    const float4 bb = *(const float4*)&b2[wave * 64 + jt * 16 + q * 4];
#pragma unroll
    for (int tt = 0; tt < 3; ++tt)
      acc[jt][tt] = (floatx4){bb.x, bb.y, bb.z, bb.w};
  }
#pragma unroll
  for (int kc = 0; kc < 8; ++kc) {
    bf16x8 a[4], b[3];
#pragma unroll
    for (int jt = 0; jt < 4; ++jt)
      a[jt] = *(const bf16x8*)(pW2 + ((((wave * 4 + jt) * 8 + kc) * 64 + lane) << 3));
#pragma unroll
    for (int tt = 0; tt < 3; ++tt) {
      const int t = tt * 16 + l15;
      b[tt] = *(const bf16x8*)&Hs[t * 512 + ((kc * 64 + q * 16) ^ SWZ(t))];
    }
    __builtin_amdgcn_s_setprio(1);
#pragma unroll
    for (int jt = 0; jt < 4; ++jt)
#pragma unroll
      for (int tt = 0; tt < 3; ++tt)
        acc[jt][tt] = __builtin_amdgcn_mfma_f32_16x16x32_bf16(
            a[jt], b[tt], acc[jt][tt], 0, 0, 0);
    __builtin_amdgcn_s_setprio(0);
  }
  __syncthreads();   // h1 reads done before overwrite
#pragma unroll
  for (int jt = 0; jt < 4; ++jt) {
    const int cb = (wave * 64 + jt * 16 + q * 4) * 2;
#pragma unroll
    for (int tt = 0; tt < 3; ++tt) {
      const int t = tt * 16 + l15;
      float v0 = fmaxf(acc[jt][tt][0], 0.f);
      float v1 = fmaxf(acc[jt][tt][1], 0.f);
      float v2 = fmaxf(acc[jt][tt][2], 0.f);
      float v3 = fmaxf(acc[jt][tt][3], 0.f);
      *(uint2*)&Hs[t * 512 + (cb ^ SWZ(t))] = make_uint2(pkbf(v0, v1), pkbf(v2, v3));
    }
  }
  __syncthreads();

  // ---- layer 3: K = 256, A = W3^T, B = h2, fused token-sum ----
#pragma unroll
  for (int jt = 0; jt < 4; ++jt) {
    const float4 bb = *(const float4*)&b3[wave * 64 + jt * 16 + q * 4];
#pragma unroll
    for (int tt = 0; tt < 3; ++tt)
      acc[jt][tt] = (floatx4){bb.x, bb.y, bb.z, bb.w};
  }
#pragma unroll
  for (int kc = 0; kc < 8; ++kc) {
    bf16x8 a[4], b[3];
#pragma unroll
    for (int jt = 0; jt < 4; ++jt)
      a[jt] = *(const bf16x8*)(pW3 + ((((wave * 4 + jt) * 8 + kc) * 64 + lane) << 3));
#pragma unroll
    for (int tt = 0; tt < 3; ++tt) {
      const int t = tt * 16 + l15;
      b[tt] = *(const bf16x8*)&Hs[t * 512 + ((kc * 64 + q * 16) ^ SWZ(t))];
    }
    __builtin_amdgcn_s_setprio(1);
#pragma unroll
    for (int jt = 0; jt < 4; ++jt)
#pragma unroll
      for (int tt = 0; tt < 3; ++tt)
        acc[jt][tt] = __builtin_amdgcn_mfma_f32_16x16x32_bf16(
            a[jt], b[tt], acc[jt][tt], 0, 0, 0);
    __builtin_amdgcn_s_setprio(0);
  }
  __syncthreads();   // h2 reads done before scratch overwrites Hs

  // relu + partial token-sum (masked for the padded tail tile); scratch rows
  // padded 17 float4 so the final read is 2-way (free), not 16-way.
  {
    float4* scratch = (float4*)Hs;
#pragma unroll
    for (int jt = 0; jt < 4; ++jt) {
      float s0 = 0.f, s1 = 0.f, s2 = 0.f, s3 = 0.f;
#pragma unroll
      for (int tt = 0; tt < 3; ++tt) {
        if (tt * 16 < valid) {   // block-uniform; valid is a multiple of 16
          s0 += fmaxf(acc[jt][tt][0], 0.f);
          s1 += fmaxf(acc[jt][tt][1], 0.f);
          s2 += fmaxf(acc[jt][tt][2], 0.f);
          s3 += fmaxf(acc[jt][tt][3], 0.f);
        }
      }
      scratch[((wave * 4 + jt) * 4 + q) * 17 + l15] = (float4){s0, s1, s2, s3};
    }
  }
  __syncthreads();
  {
    const int c = tid >> 2;
    const int r = tid & 3;
    const float* sf = (const float*)Hs;
    float v = 0.f;
#pragma unroll
    for (int l = 0; l < 16; ++l)
      v += sf[c * 68 + l * 4 + r];
    const int wv = c >> 4, jt = (c >> 2) & 3, qq = c & 3;
    const int j = wv * 64 + jt * 16 + qq * 4 + r;
    atomicAdd(&msum[batch * NHID + j], v);
  }
}

// ---------------------------------------------------------------------------
// Decoder: 128 blocks = (batch x d2-quarter), 1024 threads. Each block
// computes the full d1 (redundant x4, D1 is L2-resident), its 128-wide d2
// quarter, and atomicAdds its partial L3 dot into out (pre-init'd to c3).
// ---------------------------------------------------------------------------
__global__ __launch_bounds__(1024) void decoder(
    const float* __restrict__ msum,
    const float* __restrict__ D1, const float* __restrict__ c1,
    const float* __restrict__ D2, const float* __restrict__ c2,
    const float* __restrict__ D3,
    float* __restrict__ out) {
  __shared__ float p[NHID];
  __shared__ float d1[NDEC];
  __shared__ float d2q[128];
  __shared__ __align__(16) float red[4096];   // 16 KB
  const int b = blockIdx.x >> 2, qd = blockIdx.x & 3, t = threadIdx.x;

  if (t < NHID) {
    float m = msum[b * NHID + t] * (1.f / NTOK);
    p[t] = m * m;                        // relu(m^2) == m^2
  }
  __syncthreads();

  // ---- layer 1 (full, redundant x4): K = 256 -> 32 k per split ----
  {
    const int jg = t & 127;              // j-group of 4
    const int ks = t >> 7;               // 0..7 K-split
    const float4* D1v = (const float4*)D1;   // [256][128] float4
    float4 s = {0.f, 0.f, 0.f, 0.f};
    for (int k = ks * 32; k < ks * 32 + 32; ++k) {
      float4 w = D1v[k * 128 + jg];
      float pv = p[k];
      s.x += pv * w.x; s.y += pv * w.y; s.z += pv * w.z; s.w += pv * w.w;
    }
    *(float4*)&red[t * 4] = s;
    __syncthreads();
    if (t < NDEC) {
      float v = c1[t];
#pragma unroll
      for (int i = 0; i < 8; ++i) v += red[i * 512 + t];
      d1[t] = fmaxf(v, 0.f);
    }
    __syncthreads();
  }

  // ---- layer 2 (quarter): 128 outs, K = 512 -> 32 splits x 16 k ----
  {
    const int jg2 = t & 31;              // float4 group within quarter
    const int ks2 = t >> 5;              // 0..31 K-split
    const float4* D2v = (const float4*)D2;   // [512][128] float4
    float4 s = {0.f, 0.f, 0.f, 0.f};
    for (int k = ks2 * 16; k < ks2 * 16 + 16; ++k) {
      float4 w = D2v[k * 128 + qd * 32 + jg2];
      float hv = d1[k];
      s.x += hv * w.x; s.y += hv * w.y; s.z += hv * w.z; s.w += hv * w.w;
    }
    *(float4*)&red[t * 4] = s;           // == red[ks2*128 + jg2*4 + c]
    __syncthreads();
    if (t < 128) {
      float v = c2[qd * 128 + t];
#pragma unroll
      for (int i = 0; i < 32; ++i) v += red[i * 128 + t];
      d2q[t] = fmaxf(v, 0.f);
    }
    __syncthreads();
  }

  // ---- layer 3 partial: quarter K = 128; 64 k-chunks x 16 j-slots ----
  {
    const int j3 = t & 15;
    const int kc = t >> 4;               // 0..63, 2 k's each
    float s = 0.f;
    if (j3 < NOUTC)
      for (int k = kc * 2; k < kc * 2 + 2; ++k)
        s += d2q[k] * D3[(qd * 128 + k) * NOUTC + j3];
    red[t] = s;
    __syncthreads();
    if (t < NOUTC) {
      float v = 0.f;
#pragma unroll
      for (int i = 0; i < 64; ++i) v += red[i * 16 + t];
      atomicAdd(&out[b * NOUTC + t], v);
    }
  }
}

// ---------------------------------------------------------------------------
extern "C" void kernel_launch(void* const* d_in, const int* in_sizes, int n_in,
                              void* d_out, int out_size, void* d_ws, size_t ws_size,
                              hipStream_t stream) {
  const float* x  = (const float*)d_in[0];
  const float* W1 = (const float*)d_in[1];
  const float* b1 = (const float*)d_in[2];
  const float* W2 = (const float*)d_in[3];
  const float* b2 = (const float*)d_in[4];
  const float* W3 = (const float*)d_in[5];
  const float* b3 = (const float*)d_in[6];
  const float* D1 = (const float*)d_in[7];
  const float* c1 = (const float*)d_in[8];
  const float* D2 = (const float*)d_in[9];
  const float* c2 = (const float*)d_in[10];
  const float* D3 = (const float*)d_in[11];
  const float* c3 = (const float*)d_in[12];

  // ws: [0,320K) packed bf16 W | [384K,416K) msum
  uint16_t* pW   = (uint16_t*)d_ws;
  float*    msum = (float*)((char*)d_ws + 384 * 1024);

  pack_weights<<<640, 256, 0, stream>>>(W1, W2, W3, c3, pW, msum,
                                        (float*)d_out);
  encoder<<<NBLK, 256, 0, stream>>>(x, pW, b1, b2, b3, msum);
  decoder<<<128, 1024, 0, stream>>>(msum, D1, c1, D2, c2, D3,
                                    (float*)d_out);
}

// Round 5
// 167.109 us; speedup vs baseline: 1.8105x; 1.8105x over previous
//
#include <hip/hip_runtime.h>
#include <hip/hip_bf16.h>
#include <stdint.h>

// ---------------------------------------------------------------------------
// TensorNet: fused encoder MLP (128->256->256->256, relu) over 32x4096 tokens,
// per-batch mean -> p = relu(m^2) -> decoder MLP (256->512->512->10).
//
// R20: clean retest of MTILE 64 -> 48. R19 bundled it with
// __launch_bounds__(256,6) which forced VGPR=40 and spilled the accumulator
// (WRITE_SIZE 2MB->294MB, encoder 193us) — the tile change itself was never
// measured. This round: exact R17 kernel, only MTILE=48 (LDS 24576 -> 6
// blocks/CU by LDS; acc 64->48 VGPR so natural VGPR ~75 should allow 6
// waves/SIMD). Tail tile: 16 valid tokens, zero-padded, sum-masked
// (correctness proven in R19 which passed).
//
// HARD RULES from the log:
//  - NEVER pass a min-waves arg to __launch_bounds__ (R5, R19: spills).
//  - NEVER grow per-wave a-load count / VGPR for "sharing" (R18: 185us).
//  - Residency is the lever that pays (R17: +1 blk/CU -> -17%).
//
// Explored & rejected: MTILE=128 (R16), wave->token remap (R18),
// direct-global B-frags (R5/R6), manual ping-pong (R13), cooperative
// single-kernel (R11), decoder-in-encoder tail (R14/R15).
// R17 wins kept: XOR-swizzled LDS, bias-init acc, 128-block decoder,
// out pre-init'd to c3 by pack.
// ---------------------------------------------------------------------------

#define NIN   128
#define NHID  256
#define NDEC  512
#define NOUTC 10
#define BATCH 32
#define NTOK  4096
#define MTILE 48
#define TPB   86                          // ceil(4096/48) tiles per batch
#define NBLK  (BATCH * TPB)               // 2752 encoder tiles

#define SWZ(t) (((t) & 7) << 4)          // XOR swizzle, bits 4-6

typedef short bf16x8 __attribute__((ext_vector_type(8)));
typedef float floatx4 __attribute__((ext_vector_type(4)));

__device__ __forceinline__ uint16_t f2b(float f) {
  union { uint32_t u; float f; } v; v.f = f;
  uint32_t r = v.u + 0x7FFFu + ((v.u >> 16) & 1u);   // RNE
  return (uint16_t)(r >> 16);
}
__device__ __forceinline__ uint32_t pkbf(float lo, float hi) {
  __hip_bfloat162 h = __float22bfloat162_rn(float2{lo, hi});  // v_cvt_pk_bf16_f32
  union { __hip_bfloat162 h; uint32_t u; } c; c.h = h;
  return c.u;
}

// ---------------------------------------------------------------------------
// Pack W1/W2/W3 (fp32 [K][256] row-major) into bf16 MFMA-A-fragment order.
// Also zero-inits msum and pre-loads out with c3 (decoder atomics accumulate
// on top; pack -> encoder -> decoder are stream-ordered).
// ---------------------------------------------------------------------------
__global__ __launch_bounds__(256) void pack_weights(
    const float* __restrict__ W1, const float* __restrict__ W2,
    const float* __restrict__ W3, const float* __restrict__ c3,
    uint16_t* __restrict__ pW, float* __restrict__ msum,
    float* __restrict__ out) {
  int p = blockIdx.x * blockDim.x + threadIdx.x;
  if (p < BATCH * NHID) msum[p] = 0.f;
  if (p < BATCH * NOUTC) out[p] = c3[p % NOUTC];
  const float* W; int K; int base;
  if (p < 32768)      { W = W1; K = NIN;  base = 0; }
  else if (p < 98304) { W = W2; K = NHID; base = 32768; p -= 32768; }
  else                { W = W3; K = NHID; base = 98304; p -= 98304; }
  int j    = p & 7;
  int ln   = (p >> 3) & 63;
  int rest = p >> 9;
  int KC = K >> 5;
  int kc = rest % KC;
  int mt = rest / KC;
  int m = mt * 16 + (ln & 15);
  int k = kc * 32 + ((ln >> 4) << 3) + j;
  pW[base + (((mt * KC + kc) * 64 + ln) << 3) + j] = f2b(W[k * NHID + m]);
}

// ---------------------------------------------------------------------------
// Fused encoder. Block = 256 thr (4 waves), 48 tokens. Wave w owns hidden
// rows [64w,64w+64). LDS = 24576 B -> 6 blocks/CU by LDS; VGPR free-floats
// (~75 expected). Tail tile per batch: 16 valid tokens, zero-padded; padded
// columns flow independently and are masked out of the token-sum.
// ---------------------------------------------------------------------------
__global__ __launch_bounds__(256) void encoder(
    const float* __restrict__ x,        // [BATCH*NTOK][NIN] fp32
    const uint16_t* __restrict__ pW,
    const float* __restrict__ b1,
    const float* __restrict__ b2,
    const float* __restrict__ b3,
    float* __restrict__ msum) {         // [BATCH][NHID] fp32 accum
  __shared__ __align__(16) uint8_t Hs[MTILE * 512];   // 24576 B

  const int tid  = threadIdx.x;
  const int wave = tid >> 6;
  const int lane = tid & 63;
  const int l15  = lane & 15;
  const int q    = lane >> 4;
  const int batch = blockIdx.x / TPB;
  const int tile  = blockIdx.x - batch * TPB;
  const int valid = (tile == TPB - 1) ? (NTOK - (TPB - 1) * MTILE) : MTILE; // 16 or 48

  const uint16_t* pW1 = pW;             // KC=4
  const uint16_t* pW2 = pW + 32768;     // KC=8
  const uint16_t* pW3 = pW + 98304;     // KC=8

  // ---- stage x tile: 48 tokens x 128 ch fp32 -> bf16, row stride 256B ----
  {
    const float4* xv = (const float4*)(x + (size_t)(batch * NTOK + tile * MTILE) * NIN);
#pragma unroll
    for (int i = 0; i < 3; ++i) {
      const int u = tid + i * 256;            // 8-float unit, 0..767
      const int row = u >> 4;                 // token 0..47
      const int cb  = (u & 15) << 4;          // byte col 0..240
      uint4 w = make_uint4(0u, 0u, 0u, 0u);
      if (row < valid) {
        float4 va = xv[2 * u];
        float4 vb = xv[2 * u + 1];
        w = make_uint4(pkbf(va.x, va.y), pkbf(va.z, va.w),
                       pkbf(vb.x, vb.y), pkbf(vb.z, vb.w));
      }
      *(uint4*)&Hs[row * 256 + (cb ^ SWZ(row))] = w;
    }
  }
  __syncthreads();

  floatx4 acc[4][3];   // [jt][tt]

  // ---- layer 1: K = 128, A = W1^T, B = x; acc init = bias ----
#pragma unroll
  for (int jt = 0; jt < 4; ++jt) {
    const float4 bb = *(const float4*)&b1[wave * 64 + jt * 16 + q * 4];
#pragma unroll
    for (int tt = 0; tt < 3; ++tt)
      acc[jt][tt] = (floatx4){bb.x, bb.y, bb.z, bb.w};
  }
#pragma unroll
  for (int kc = 0; kc < 4; ++kc) {
    bf16x8 a[4], b[3];
#pragma unroll
    for (int jt = 0; jt < 4; ++jt)
      a[jt] = *(const bf16x8*)(pW1 + ((((wave * 4 + jt) * 4 + kc) * 64 + lane) << 3));
#pragma unroll
    for (int tt = 0; tt < 3; ++tt) {
      const int t = tt * 16 + l15;
      b[tt] = *(const bf16x8*)&Hs[t * 256 + ((kc * 64 + q * 16) ^ SWZ(t))];
    }
#pragma unroll
    for (int jt = 0; jt < 4; ++jt)
#pragma unroll
      for (int tt = 0; tt < 3; ++tt)
        acc[jt][tt] = __builtin_amdgcn_mfma_f32_16x16x32_bf16(
            a[jt], b[tt], acc[jt][tt], 0, 0, 0);
  }
  __syncthreads();   // x reads done before h1 overwrites

#pragma unroll
  for (int jt = 0; jt < 4; ++jt) {
    const int cb = (wave * 64 + jt * 16 + q * 4) * 2;
#pragma unroll
    for (int tt = 0; tt < 3; ++tt) {
      const int t = tt * 16 + l15;
      float v0 = fmaxf(acc[jt][tt][0], 0.f);
      float v1 = fmaxf(acc[jt][tt][1], 0.f);
      float v2 = fmaxf(acc[jt][tt][2], 0.f);
      float v3 = fmaxf(acc[jt][tt][3], 0.f);
      *(uint2*)&Hs[t * 512 + (cb ^ SWZ(t))] = make_uint2(pkbf(v0, v1), pkbf(v2, v3));
    }
  }
  __syncthreads();

  // ---- layer 2: K = 256, A = W2^T, B = h1 ----
#pragma unroll
  for (int jt = 0; jt < 4; ++jt) {
    const float4 bb = *(const float4*)&b2[wave * 64 + jt * 16 + q * 4];
#pragma unroll
    for (int tt = 0; tt < 3; ++tt)
      acc[jt][tt] = (floatx4){bb.x, bb.y, bb.z, bb.w};
  }
#pragma unroll
  for (int kc = 0; kc < 8; ++kc) {
    bf16x8 a[4], b[3];
#pragma unroll
    for (int jt = 0; jt < 4; ++jt)
      a[jt] = *(const bf16x8*)(pW2 + ((((wave * 4 + jt) * 8 + kc) * 64 + lane) << 3));
#pragma unroll
    for (int tt = 0; tt < 3; ++tt) {
      const int t = tt * 16 + l15;
      b[tt] = *(const bf16x8*)&Hs[t * 512 + ((kc * 64 + q * 16) ^ SWZ(t))];
    }
#pragma unroll
    for (int jt = 0; jt < 4; ++jt)
#pragma unroll
      for (int tt = 0; tt < 3; ++tt)
        acc[jt][tt] = __builtin_amdgcn_mfma_f32_16x16x32_bf16(
            a[jt], b[tt], acc[jt][tt], 0, 0, 0);
  }
  __syncthreads();   // h1 reads done before overwrite
#pragma unroll
  for (int jt = 0; jt < 4; ++jt) {
    const int cb = (wave * 64 + jt * 16 + q * 4) * 2;
#pragma unroll
    for (int tt = 0; tt < 3; ++tt) {
      const int t = tt * 16 + l15;
      float v0 = fmaxf(acc[jt][tt][0], 0.f);
      float v1 = fmaxf(acc[jt][tt][1], 0.f);
      float v2 = fmaxf(acc[jt][tt][2], 0.f);
      float v3 = fmaxf(acc[jt][tt][3], 0.f);
      *(uint2*)&Hs[t * 512 + (cb ^ SWZ(t))] = make_uint2(pkbf(v0, v1), pkbf(v2, v3));
    }
  }
  __syncthreads();

  // ---- layer 3: K = 256, A = W3^T, B = h2, fused token-sum ----
#pragma unroll
  for (int jt = 0; jt < 4; ++jt) {
    const float4 bb = *(const float4*)&b3[wave * 64 + jt * 16 + q * 4];
#pragma unroll
    for (int tt = 0; tt < 3; ++tt)
      acc[jt][tt] = (floatx4){bb.x, bb.y, bb.z, bb.w};
  }
#pragma unroll
  for (int kc = 0; kc < 8; ++kc) {
    bf16x8 a[4], b[3];
#pragma unroll
    for (int jt = 0; jt < 4; ++jt)
      a[jt] = *(const bf16x8*)(pW3 + ((((wave * 4 + jt) * 8 + kc) * 64 + lane) << 3));
#pragma unroll
    for (int tt = 0; tt < 3; ++tt) {
      const int t = tt * 16 + l15;
      b[tt] = *(const bf16x8*)&Hs[t * 512 + ((kc * 64 + q * 16) ^ SWZ(t))];
    }
#pragma unroll
    for (int jt = 0; jt < 4; ++jt)
#pragma unroll
      for (int tt = 0; tt < 3; ++tt)
        acc[jt][tt] = __builtin_amdgcn_mfma_f32_16x16x32_bf16(
            a[jt], b[tt], acc[jt][tt], 0, 0, 0);
  }
  __syncthreads();   // h2 reads done before scratch overwrites Hs

  // relu + partial token-sum (masked for the padded tail tile); scratch rows
  // padded 17 float4 so the final read is 2-way (free), not 16-way.
  {
    float4* scratch = (float4*)Hs;
#pragma unroll
    for (int jt = 0; jt < 4; ++jt) {
      float s0 = 0.f, s1 = 0.f, s2 = 0.f, s3 = 0.f;
#pragma unroll
      for (int tt = 0; tt < 3; ++tt) {
        if (tt * 16 < valid) {   // block-uniform; valid is a multiple of 16
          s0 += fmaxf(acc[jt][tt][0], 0.f);
          s1 += fmaxf(acc[jt][tt][1], 0.f);
          s2 += fmaxf(acc[jt][tt][2], 0.f);
          s3 += fmaxf(acc[jt][tt][3], 0.f);
        }
      }
      scratch[((wave * 4 + jt) * 4 + q) * 17 + l15] = (float4){s0, s1, s2, s3};
    }
  }
  __syncthreads();
  {
    const int c = tid >> 2;
    const int r = tid & 3;
    const float* sf = (const float*)Hs;
    float v = 0.f;
#pragma unroll
    for (int l = 0; l < 16; ++l)
      v += sf[c * 68 + l * 4 + r];
    const int wv = c >> 4, jt = (c >> 2) & 3, qq = c & 3;
    const int j = wv * 64 + jt * 16 + qq * 4 + r;
    atomicAdd(&msum[batch * NHID + j], v);
  }
}

// ---------------------------------------------------------------------------
// Decoder: 128 blocks = (batch x d2-quarter), 1024 threads. Each block
// computes the full d1 (redundant x4, D1 is L2-resident), its 128-wide d2
// quarter, and atomicAdds its partial L3 dot into out (pre-init'd to c3).
// ---------------------------------------------------------------------------
__global__ __launch_bounds__(1024) void decoder(
    const float* __restrict__ msum,
    const float* __restrict__ D1, const float* __restrict__ c1,
    const float* __restrict__ D2, const float* __restrict__ c2,
    const float* __restrict__ D3,
    float* __restrict__ out) {
  __shared__ float p[NHID];
  __shared__ float d1[NDEC];
  __shared__ float d2q[128];
  __shared__ __align__(16) float red[4096];   // 16 KB
  const int b = blockIdx.x >> 2, qd = blockIdx.x & 3, t = threadIdx.x;

  if (t < NHID) {
    float m = msum[b * NHID + t] * (1.f / NTOK);
    p[t] = m * m;                        // relu(m^2) == m^2
  }
  __syncthreads();

  // ---- layer 1 (full, redundant x4): K = 256 -> 32 k per split ----
  {
    const int jg = t & 127;              // j-group of 4
    const int ks = t >> 7;               // 0..7 K-split
    const float4* D1v = (const float4*)D1;   // [256][128] float4
    float4 s = {0.f, 0.f, 0.f, 0.f};
    for (int k = ks * 32; k < ks * 32 + 32; ++k) {
      float4 w = D1v[k * 128 + jg];
      float pv = p[k];
      s.x += pv * w.x; s.y += pv * w.y; s.z += pv * w.z; s.w += pv * w.w;
    }
    *(float4*)&red[t * 4] = s;
    __syncthreads();
    if (t < NDEC) {
      float v = c1[t];
#pragma unroll
      for (int i = 0; i < 8; ++i) v += red[i * 512 + t];
      d1[t] = fmaxf(v, 0.f);
    }
    __syncthreads();
  }

  // ---- layer 2 (quarter): 128 outs, K = 512 -> 32 splits x 16 k ----
  {
    const int jg2 = t & 31;              // float4 group within quarter
    const int ks2 = t >> 5;              // 0..31 K-split
    const float4* D2v = (const float4*)D2;   // [512][128] float4
    float4 s = {0.f, 0.f, 0.f, 0.f};
    for (int k = ks2 * 16; k < ks2 * 16 + 16; ++k) {
      float4 w = D2v[k * 128 + qd * 32 + jg2];
      float hv = d1[k];
      s.x += hv * w.x; s.y += hv * w.y; s.z += hv * w.z; s.w += hv * w.w;
    }
    *(float4*)&red[t * 4] = s;           // == red[ks2*128 + jg2*4 + c]
    __syncthreads();
    if (t < 128) {
      float v = c2[qd * 128 + t];
#pragma unroll
      for (int i = 0; i < 32; ++i) v += red[i * 128 + t];
      d2q[t] = fmaxf(v, 0.f);
    }
    __syncthreads();
  }

  // ---- layer 3 partial: quarter K = 128; 64 k-chunks x 16 j-slots ----
  {
    const int j3 = t & 15;
    const int kc = t >> 4;               // 0..63, 2 k's each
    float s = 0.f;
    if (j3 < NOUTC)
      for (int k = kc * 2; k < kc * 2 + 2; ++k)
        s += d2q[k] * D3[(qd * 128 + k) * NOUTC + j3];
    red[t] = s;
    __syncthreads();
    if (t < NOUTC) {
      float v = 0.f;
#pragma unroll
      for (int i = 0; i < 64; ++i) v += red[i * 16 + t];
      atomicAdd(&out[b * NOUTC + t], v);
    }
  }
}

// ---------------------------------------------------------------------------
extern "C" void kernel_launch(void* const* d_in, const int* in_sizes, int n_in,
                              void* d_out, int out_size, void* d_ws, size_t ws_size,
                              hipStream_t stream) {
  const float* x  = (const float*)d_in[0];
  const float* W1 = (const float*)d_in[1];
  const float* b1 = (const float*)d_in[2];
  const float* W2 = (const float*)d_in[3];
  const float* b2 = (const float*)d_in[4];
  const float* W3 = (const float*)d_in[5];
  const float* b3 = (const float*)d_in[6];
  const float* D1 = (const float*)d_in[7];
  const float* c1 = (const float*)d_in[8];
  const float* D2 = (const float*)d_in[9];
  const float* c2 = (const float*)d_in[10];
  const float* D3 = (const float*)d_in[11];
  const float* c3 = (const float*)d_in[12];

  // ws: [0,320K) packed bf16 W | [384K,416K) msum
  uint16_t* pW   = (uint16_t*)d_ws;
  float*    msum = (float*)((char*)d_ws + 384 * 1024);

  pack_weights<<<640, 256, 0, stream>>>(W1, W2, W3, c3, pW, msum,
                                        (float*)d_out);
  encoder<<<NBLK, 256, 0, stream>>>(x, pW, b1, b2, b3, msum);
  decoder<<<128, 1024, 0, stream>>>(msum, D1, c1, D2, c2, D3,
                                    (float*)d_out);
}